// Round 1
// baseline (9200.578 us; speedup 1.0000x reference)
//
#include <hip/hip_runtime.h>
#include <hip/hip_bf16.h>
#include <cstdint>
#include <cstddef>

// Wave-synchronous LDS handoff: lanes of one wave run in lockstep on CDNA;
// s_waitcnt lgkmcnt(0) guarantees prior ds_write/ds_read completion.
#define WAVE_SYNC() asm volatile("s_waitcnt lgkmcnt(0)" ::: "memory")

__device__ __forceinline__ float sigmoid_f(float x) {
  x = fminf(fmaxf(x, -30.f), 30.f);
  return 1.f / (1.f + __expf(-x));
}
__device__ __forceinline__ float tanh_f(float x) {
  x = fminf(fmaxf(x, -15.f), 15.f);
  float e = __expf(-2.f * x);
  return (1.f - e) / (1.f + e);
}

// One LSTM layer, PyTorch gate order (i,f,g,o).
// Grid: 256 blocks x 128 threads. Wave w of block bl handles batch b = bl*2+w.
// IN_MODE:  0 = f32 sequence [B,T,D], 1 = bf16 sequence [B,T,D],
//           2 = f32 latent [B,D] broadcast over time (decoder input)
// OUT_MODE: 0 = f32 sequence [B,T,H], 1 = bf16 sequence [B,T,H],
//           2 = f32 last-h only [B,H]
template <int D, int H, int IN_MODE, int OUT_MODE>
__launch_bounds__(128)
__global__ void lstm_layer(const float* __restrict__ Wih, const float* __restrict__ Whh,
                           const float* __restrict__ bih, const float* __restrict__ bhh,
                           const void* __restrict__ inp, void* __restrict__ outp, int T) {
  constexpr int G = 4 * H;   // gate vector width (multiple of 64 for all layers)
  constexpr int P = G / 64;  // gate outputs per lane
  extern __shared__ float lds[];
  float* wT   = lds;           // [D][G]  Wih transposed
  float* uT   = wT + D * G;    // [H][G]  Whh transposed
  float* bias = uT + H * G;    // [G]
  float* xb   = bias + G;      // [2][D] per-wave input vector
  float* hb   = xb + 2 * D;    // [2][H] per-wave hidden state
  float* gb   = hb + 2 * H;    // [2][G] per-wave gate pre-activations

  const int tid = threadIdx.x;
  // Cooperative load + transpose of weights into LDS (one copy per block).
  for (int idx = tid; idx < G * D; idx += 128) {
    int j = idx / D, d = idx - j * D;
    wT[d * G + j] = Wih[idx];
  }
  for (int idx = tid; idx < G * H; idx += 128) {
    int j = idx / H, k = idx - j * H;
    uT[k * G + j] = Whh[idx];
  }
  for (int idx = tid; idx < G; idx += 128) bias[idx] = bih[idx] + bhh[idx];
  __syncthreads();

  const int w = tid >> 6;
  const int lane = tid & 63;
  const int b = blockIdx.x * 2 + w;
  float* xv = xb + w * D;
  float* hv = hb + w * H;
  float* gv = gb + w * G;

  if (lane < H) hv[lane] = 0.f;  // h0 = 0
  float c = 0.f;                 // lane k (< H) owns cell state c_k
  float base[P];                 // bias (+ constant input contribution for latent mode)
#pragma unroll
  for (int p = 0; p < P; ++p) base[p] = bias[lane + 64 * p];

  if (IN_MODE == 2) {
    const float* lat = (const float*)inp;
    if (lane < D) xv[lane] = lat[b * D + lane];
    WAVE_SYNC();
    for (int d = 0; d < D; ++d) {
      float xd = xv[d];
#pragma unroll
      for (int p = 0; p < P; ++p) base[p] = fmaf(wT[d * G + lane + 64 * p], xd, base[p]);
    }
  }
  WAVE_SYNC();  // hv init (and xv for latent mode) visible to all lanes

  for (int t = 0; t < T; ++t) {
    float acc[P];
#pragma unroll
    for (int p = 0; p < P; ++p) acc[p] = base[p];

    if (IN_MODE == 0) {
      const float* xin = (const float*)inp;
      if (lane < D) xv[lane] = xin[((size_t)b * T + t) * D + lane];
      WAVE_SYNC();
    } else if (IN_MODE == 1) {
      const __hip_bfloat16* xin = (const __hip_bfloat16*)inp;
      if (lane < D) xv[lane] = __bfloat162float(xin[((size_t)b * T + t) * D + lane]);
      WAVE_SYNC();
    }
    if (IN_MODE != 2) {
      for (int d = 0; d < D; ++d) {
        float xd = xv[d];  // LDS broadcast (uniform address)
#pragma unroll
        for (int p = 0; p < P; ++p) acc[p] = fmaf(wT[d * G + lane + 64 * p], xd, acc[p]);
      }
    }
    for (int k = 0; k < H; ++k) {
      float hk = hv[k];
#pragma unroll
      for (int p = 0; p < P; ++p) acc[p] = fmaf(uT[k * G + lane + 64 * p], hk, acc[p]);
    }
#pragma unroll
    for (int p = 0; p < P; ++p) gv[lane + 64 * p] = acc[p];
    WAVE_SYNC();  // also guarantees all hv reads above completed before hv write below
    if (lane < H) {
      float gi = sigmoid_f(gv[lane]);
      float gf = sigmoid_f(gv[H + lane]);
      float gg = tanh_f(gv[2 * H + lane]);
      float go = sigmoid_f(gv[3 * H + lane]);
      c = fmaf(gf, c, gi * gg);
      float h = go * tanh_f(c);
      hv[lane] = h;
      if (OUT_MODE == 0) {
        ((float*)outp)[((size_t)b * T + t) * H + lane] = h;
      } else if (OUT_MODE == 1) {
        ((__hip_bfloat16*)outp)[((size_t)b * T + t) * H + lane] = __float2bfloat16(h);
      } else if (t == T - 1) {
        ((float*)outp)[b * H + lane] = h;
      }
    }
    WAVE_SYNC();  // hv(t) ready for t+1
  }
}

static inline size_t ldsb(int D, int H) {
  int G = 4 * H;
  return (size_t)(D * G + H * G + G + 2 * (D + H + G)) * sizeof(float);
}

extern "C" void kernel_launch(void* const* d_in, const int* in_sizes, int n_in,
                              void* d_out, int out_size, void* d_ws, size_t ws_size,
                              hipStream_t stream) {
  (void)in_sizes; (void)n_in; (void)out_size;
  const float* x = (const float*)d_in[0];
  const float *W[6], *U[6], *Bi[6], *Bh[6];
  for (int l = 0; l < 6; ++l) {
    W[l]  = (const float*)d_in[1 + 4 * l + 0];
    U[l]  = (const float*)d_in[1 + 4 * l + 1];
    Bi[l] = (const float*)d_in[1 + 4 * l + 2];
    Bh[l] = (const float*)d_in[1 + 4 * l + 3];
  }
  float* out = (float*)d_out;
  const int T = 512;
  dim3 grid(256), block(128);

  auto seta = [](const void* f, size_t bytes) {
    (void)hipFuncSetAttribute(f, hipFuncAttributeMaxDynamicSharedMemorySize, (int)bytes);
  };

  const size_t szA32 = (size_t)512 * 512 * 48 * 4;  // 50.3 MB
  const size_t szB32 = (size_t)512 * 512 * 32 * 4;  // 33.6 MB
  const size_t szLat = (size_t)512 * 16 * 4;
  char* ws = (char*)d_ws;
  const bool f32path = ws_size >= szA32 + szB32 + szLat;

  if (f32path) {
    float* A   = (float*)ws;
    float* Bf  = (float*)(ws + szA32);
    float* lat = (float*)(ws + szA32 + szB32);
    seta((const void*)&lstm_layer<64, 48, 0, 0>, ldsb(64, 48));
    seta((const void*)&lstm_layer<48, 32, 0, 0>, ldsb(48, 32));
    seta((const void*)&lstm_layer<32, 16, 0, 2>, ldsb(32, 16));
    seta((const void*)&lstm_layer<16, 32, 2, 0>, ldsb(16, 32));
    seta((const void*)&lstm_layer<32, 48, 0, 0>, ldsb(32, 48));
    seta((const void*)&lstm_layer<48, 64, 0, 0>, ldsb(48, 64));
    lstm_layer<64, 48, 0, 0><<<grid, block, ldsb(64, 48), stream>>>(W[0], U[0], Bi[0], Bh[0], x,   A,   T);
    lstm_layer<48, 32, 0, 0><<<grid, block, ldsb(48, 32), stream>>>(W[1], U[1], Bi[1], Bh[1], A,   Bf,  T);
    lstm_layer<32, 16, 0, 2><<<grid, block, ldsb(32, 16), stream>>>(W[2], U[2], Bi[2], Bh[2], Bf,  lat, T);
    lstm_layer<16, 32, 2, 0><<<grid, block, ldsb(16, 32), stream>>>(W[3], U[3], Bi[3], Bh[3], lat, Bf,  T);
    lstm_layer<32, 48, 0, 0><<<grid, block, ldsb(32, 48), stream>>>(W[4], U[4], Bi[4], Bh[4], Bf,  A,   T);
    lstm_layer<48, 64, 0, 0><<<grid, block, ldsb(48, 64), stream>>>(W[5], U[5], Bi[5], Bh[5], A,   out, T);
  } else {
    const size_t szA16 = szA32 / 2, szB16 = szB32 / 2;
    __hip_bfloat16* A  = (__hip_bfloat16*)ws;
    __hip_bfloat16* Bf = (__hip_bfloat16*)(ws + szA16);
    float* lat = (float*)(ws + szA16 + szB16);
    seta((const void*)&lstm_layer<64, 48, 0, 1>, ldsb(64, 48));
    seta((const void*)&lstm_layer<48, 32, 1, 1>, ldsb(48, 32));
    seta((const void*)&lstm_layer<32, 16, 1, 2>, ldsb(32, 16));
    seta((const void*)&lstm_layer<16, 32, 2, 1>, ldsb(16, 32));
    seta((const void*)&lstm_layer<32, 48, 1, 1>, ldsb(32, 48));
    seta((const void*)&lstm_layer<48, 64, 1, 0>, ldsb(48, 64));
    lstm_layer<64, 48, 0, 1><<<grid, block, ldsb(64, 48), stream>>>(W[0], U[0], Bi[0], Bh[0], x,   A,   T);
    lstm_layer<48, 32, 1, 1><<<grid, block, ldsb(48, 32), stream>>>(W[1], U[1], Bi[1], Bh[1], A,   Bf,  T);
    lstm_layer<32, 16, 1, 2><<<grid, block, ldsb(32, 16), stream>>>(W[2], U[2], Bi[2], Bh[2], Bf,  lat, T);
    lstm_layer<16, 32, 2, 1><<<grid, block, ldsb(16, 32), stream>>>(W[3], U[3], Bi[3], Bh[3], lat, Bf,  T);
    lstm_layer<32, 48, 1, 1><<<grid, block, ldsb(32, 48), stream>>>(W[4], U[4], Bi[4], Bh[4], Bf,  A,   T);
    lstm_layer<48, 64, 1, 0><<<grid, block, ldsb(48, 64), stream>>>(W[5], U[5], Bi[5], Bh[5], A,   out, T);
  }
}

// Round 2
// 2187.597 us; speedup vs baseline: 4.2058x; 4.2058x over previous
//
#include <hip/hip_runtime.h>
#include <hip/hip_bf16.h>
#include <cstdint>
#include <cstddef>

__device__ __forceinline__ float sigmoid_f(float x) {
  x = fminf(fmaxf(x, -30.f), 30.f);
  return 1.f / (1.f + __expf(-x));
}
__device__ __forceinline__ float tanh_f(float x) {
  x = fminf(fmaxf(x, -15.f), 15.f);
  float e = __expf(-2.f * x);
  return (1.f - e) / (1.f + e);
}

// One LSTM layer. One block per batch chain (512 blocks x 256 threads).
// The 4 waves of a block are the 4 gate types (i,f,g,o); lane k (<H) of wave w
// owns gate row r = w*H+k, with Wih[r][:], Whh[r][:] held in VGPRs.
// x_t / h_{t-1} are broadcast from LDS via uniform float4 reads.
// All 4 waves redundantly maintain c_k (consistent: same inputs, same math).
// IN_MODE:  0 = f32 seq [B,T,D], 1 = bf16 seq, 2 = f32 latent [B,D] (constant over t)
// OUT_MODE: 0 = f32 seq [B,T,H], 1 = bf16 seq, 2 = f32 last-h [B,H]
template <int D, int H, int IN_MODE, int OUT_MODE>
__launch_bounds__(256, 2)
__global__ void lstm4(const float* __restrict__ Wih, const float* __restrict__ Whh,
                      const float* __restrict__ bih, const float* __restrict__ bhh,
                      const void* __restrict__ inp, void* __restrict__ outp, int T) {
  alignas(16) __shared__ float xbuf[64];
  alignas(16) __shared__ float hbuf[64];
  alignas(16) __shared__ float gbuf[64][4];  // [hidden k][gate type]

  const int tid = threadIdx.x;
  const int w = tid >> 6;   // gate type 0..3 = i,f,g,o
  const int k = tid & 63;   // hidden unit
  const int b = blockIdx.x;
  const bool act = (k < H);

  float wih[D], whh[H];
  float base = 0.f;
  if (act) {
    const int r = w * H + k;
    const float4* wp = (const float4*)(Wih + (size_t)r * D);
#pragma unroll
    for (int d4 = 0; d4 < D / 4; ++d4) {
      float4 q = wp[d4];
      wih[4 * d4 + 0] = q.x; wih[4 * d4 + 1] = q.y;
      wih[4 * d4 + 2] = q.z; wih[4 * d4 + 3] = q.w;
    }
    const float4* up = (const float4*)(Whh + (size_t)r * H);
#pragma unroll
    for (int j4 = 0; j4 < H / 4; ++j4) {
      float4 q = up[j4];
      whh[4 * j4 + 0] = q.x; whh[4 * j4 + 1] = q.y;
      whh[4 * j4 + 2] = q.z; whh[4 * j4 + 3] = q.w;
    }
    base = bih[r] + bhh[r];
    if (IN_MODE == 2) {  // constant input: fold Wih*latent into the bias
      const float* lat = (const float*)inp;
#pragma unroll
      for (int d = 0; d < D; ++d) base = fmaf(wih[d], lat[b * D + d], base);
    }
  }
  if (tid < 64) hbuf[tid] = 0.f;
  if (IN_MODE == 0 && w == 0 && k < D)
    xbuf[k] = ((const float*)inp)[(size_t)b * T * D + k];
  if (IN_MODE == 1 && w == 0 && k < D)
    xbuf[k] = __bfloat162float(((const __hip_bfloat16*)inp)[(size_t)b * T * D + k]);
  __syncthreads();

  float c = 0.f;
  for (int t = 0; t < T; ++t) {
    // ---- compute phase: gate pre-activation from registers + LDS broadcasts
    if (act) {
      float a0 = base, a1 = 0.f, a2 = 0.f, a3 = 0.f;
      if (IN_MODE != 2) {
#pragma unroll
        for (int d4 = 0; d4 < D / 4; ++d4) {
          float4 xq = *(const float4*)&xbuf[4 * d4];  // uniform addr: broadcast
          a0 = fmaf(wih[4 * d4 + 0], xq.x, a0);
          a1 = fmaf(wih[4 * d4 + 1], xq.y, a1);
          a2 = fmaf(wih[4 * d4 + 2], xq.z, a2);
          a3 = fmaf(wih[4 * d4 + 3], xq.w, a3);
        }
      }
#pragma unroll
      for (int j4 = 0; j4 < H / 4; ++j4) {
        float4 hq = *(const float4*)&hbuf[4 * j4];  // uniform addr: broadcast
        a0 = fmaf(whh[4 * j4 + 0], hq.x, a0);
        a1 = fmaf(whh[4 * j4 + 1], hq.y, a1);
        a2 = fmaf(whh[4 * j4 + 2], hq.z, a2);
        a3 = fmaf(whh[4 * j4 + 3], hq.w, a3);
      }
      float pre = (a0 + a1) + (a2 + a3);
      float g = (w == 2) ? tanh_f(pre) : sigmoid_f(pre);
      gbuf[k][w] = g;  // activated gate
    }
    // prefetch next timestep's input into registers (off critical path)
    float xpre = 0.f;
    const bool pf = (IN_MODE != 2) && (w == 0) && (k < D) && (t + 1 < T);
    if (pf) {
      if (IN_MODE == 0)
        xpre = ((const float*)inp)[((size_t)b * T + t + 1) * D + k];
      else
        xpre = __bfloat162float(((const __hip_bfloat16*)inp)[((size_t)b * T + t + 1) * D + k]);
    }
    __syncthreads();  // gates visible

    if (act) {
      float4 g4 = *(const float4*)&gbuf[k][0];  // one b128, lane-strided
      c = fmaf(g4.y, c, g4.x * g4.z);           // c = f*c + i*g
      float h = g4.w * tanh_f(c);               // h = o*tanh(c)
      if (w == 3) {
        hbuf[k] = h;
        if (OUT_MODE == 0)
          ((float*)outp)[((size_t)b * T + t) * H + k] = h;
        else if (OUT_MODE == 1)
          ((__hip_bfloat16*)outp)[((size_t)b * T + t) * H + k] = __float2bfloat16(h);
        else if (t == T - 1)
          ((float*)outp)[(size_t)b * H + k] = h;
      }
    }
    if (pf) xbuf[k] = xpre;  // stage x_{t+1}
    __syncthreads();         // h and x_{t+1} visible
  }
}

extern "C" void kernel_launch(void* const* d_in, const int* in_sizes, int n_in,
                              void* d_out, int out_size, void* d_ws, size_t ws_size,
                              hipStream_t stream) {
  (void)in_sizes; (void)n_in; (void)out_size;
  const float* x = (const float*)d_in[0];
  const float *W[6], *U[6], *Bi[6], *Bh[6];
  for (int l = 0; l < 6; ++l) {
    W[l]  = (const float*)d_in[1 + 4 * l + 0];
    U[l]  = (const float*)d_in[1 + 4 * l + 1];
    Bi[l] = (const float*)d_in[1 + 4 * l + 2];
    Bh[l] = (const float*)d_in[1 + 4 * l + 3];
  }
  float* out = (float*)d_out;
  const int T = 512;
  dim3 grid(512), block(256);

  const size_t szA32 = (size_t)512 * 512 * 48 * 4;  // 50.3 MB
  const size_t szB32 = (size_t)512 * 512 * 32 * 4;  // 33.6 MB
  const size_t szLat = (size_t)512 * 16 * 4;
  char* ws = (char*)d_ws;

  if (ws_size >= szA32 + szB32 + szLat) {
    float* A   = (float*)ws;
    float* Bf  = (float*)(ws + szA32);
    float* lat = (float*)(ws + szA32 + szB32);
    lstm4<64, 48, 0, 0><<<grid, block, 0, stream>>>(W[0], U[0], Bi[0], Bh[0], x,   A,   T);
    lstm4<48, 32, 0, 0><<<grid, block, 0, stream>>>(W[1], U[1], Bi[1], Bh[1], A,   Bf,  T);
    lstm4<32, 16, 0, 2><<<grid, block, 0, stream>>>(W[2], U[2], Bi[2], Bh[2], Bf,  lat, T);
    lstm4<16, 32, 2, 0><<<grid, block, 0, stream>>>(W[3], U[3], Bi[3], Bh[3], lat, Bf,  T);
    lstm4<32, 48, 0, 0><<<grid, block, 0, stream>>>(W[4], U[4], Bi[4], Bh[4], Bf,  A,   T);
    lstm4<48, 64, 0, 0><<<grid, block, 0, stream>>>(W[5], U[5], Bi[5], Bh[5], A,   out, T);
  } else {
    const size_t szA16 = szA32 / 2, szB16 = szB32 / 2;
    __hip_bfloat16* A  = (__hip_bfloat16*)ws;
    __hip_bfloat16* Bf = (__hip_bfloat16*)(ws + szA16);
    float* lat = (float*)(ws + szA16 + szB16);
    lstm4<64, 48, 0, 1><<<grid, block, 0, stream>>>(W[0], U[0], Bi[0], Bh[0], x,   A,   T);
    lstm4<48, 32, 1, 1><<<grid, block, 0, stream>>>(W[1], U[1], Bi[1], Bh[1], A,   Bf,  T);
    lstm4<32, 16, 1, 2><<<grid, block, 0, stream>>>(W[2], U[2], Bi[2], Bh[2], Bf,  lat, T);
    lstm4<16, 32, 2, 1><<<grid, block, 0, stream>>>(W[3], U[3], Bi[3], Bh[3], lat, Bf,  T);
    lstm4<32, 48, 1, 1><<<grid, block, 0, stream>>>(W[4], U[4], Bi[4], Bh[4], Bf,  A,   T);
    lstm4<48, 64, 1, 0><<<grid, block, 0, stream>>>(W[5], U[5], Bi[5], Bh[5], A,   out, T);
  }
}